// Round 1
// 79.092 us; speedup vs baseline: 1.0118x; 1.0118x over previous
//
#include <hip/hip_runtime.h>
#include <math.h>

#define NC 14        // classes / centroids
#define BB 32        // batch
#define NN 16384     // subsampled points per batch
#define PP 4096      // origin points per batch

// ws layout (floats):
//   [64 .. 64+256)    per-block partial (distance; +chamfer on first block/batch)
#define WS_DIST    64
#define BLK_PER_B  8                    // 8 distance blocks per batch
#define NBLK_B     (BB * BLK_PER_B)     // 256 blocks == 256 CUs

// Fused kernel: one block per (batch, slice). Each block FIRST redundantly
// computes its batch's 14 centroids from origin+target (8 blocks/batch do the
// same ~64KB read -> L2/L3-absorbed; ~1 us of masked FMAs), THEN does its
// 2048-point distance-loss slice. First block of each batch adds chamfer +
// separation. Partial -> ws slot; a separate 1-block kernel reduces.
// No atomic counter, no ws-state dependence, replay-safe.
__global__ __launch_bounds__(256) void fused_loss_kernel(
    const float* __restrict__ disp,   // [B,N]
    const float* __restrict__ sub,    // [B,3,N]
    const float* __restrict__ cpred,  // [B,3,C]
    const float* __restrict__ origin, // [B,9,P]
    const int*   __restrict__ target, // [B,P] (int32 on device: jax x64 off)
    float* __restrict__ ws) {
    const int b    = blockIdx.x / BLK_PER_B;
    const int j    = blockIdx.x % BLK_PER_B;
    const int tid  = threadIdx.x;
    const int lane = tid & 63;
    const int wave = tid >> 6;

    // ---------- Phase 1: per-batch centroids (redundant per block) ----------
    const float* ob = origin + (size_t)b * 9 * PP;
    const int*   tb = target + (size_t)b * PP;

    float sx[NC], sy[NC], sz[NC], cn[NC];
    #pragma unroll
    for (int c = 0; c < NC; ++c) { sx[c] = sy[c] = sz[c] = cn[c] = 0.f; }

    const int p0 = tid * 4;
    #pragma unroll
    for (int it = 0; it < PP / 1024; ++it) {   // 4 iters, 16 pts/thread
        const int p = p0 + it * 1024;
        const int4   tv = *(const int4*)&tb[p];
        const float4 xv = *(const float4*)&ob[p];
        const float4 yv = *(const float4*)&ob[PP + p];
        const float4 zv = *(const float4*)&ob[2 * PP + p];
        const int   ts[4] = {tv.x, tv.y, tv.z, tv.w};
        const float xs[4] = {xv.x, xv.y, xv.z, xv.w};
        const float ys[4] = {yv.x, yv.y, yv.z, yv.w};
        const float zs[4] = {zv.x, zv.y, zv.z, zv.w};
        #pragma unroll
        for (int k = 0; k < 4; ++k) {
            #pragma unroll
            for (int c = 0; c < NC; ++c) {
                const float m = (ts[k] == c) ? 1.f : 0.f;
                sx[c] = fmaf(m, xs[k], sx[c]);
                sy[c] = fmaf(m, ys[k], sy[c]);
                sz[c] = fmaf(m, zs[k], sz[c]);
                cn[c] += m;
            }
        }
    }

    // wave-level butterfly reduce of all 56 accumulators
    #pragma unroll
    for (int c = 0; c < NC; ++c) {
        #pragma unroll
        for (int o = 32; o > 0; o >>= 1) {
            sx[c] += __shfl_down(sx[c], o);
            sy[c] += __shfl_down(sy[c], o);
            sz[c] += __shfl_down(sz[c], o);
            cn[c] += __shfl_down(cn[c], o);
        }
    }

    __shared__ float s_wsum[4][NC][4];
    if (lane == 0) {
        #pragma unroll
        for (int c = 0; c < NC; ++c) {
            s_wsum[wave][c][0] = sx[c];
            s_wsum[wave][c][1] = sy[c];
            s_wsum[wave][c][2] = sz[c];
            s_wsum[wave][c][3] = cn[c];
        }
    }
    __syncthreads();

    __shared__ float s_cent[NC * 3];
    if (tid < NC) {
        const float X = s_wsum[0][tid][0] + s_wsum[1][tid][0] + s_wsum[2][tid][0] + s_wsum[3][tid][0];
        const float Y = s_wsum[0][tid][1] + s_wsum[1][tid][1] + s_wsum[2][tid][1] + s_wsum[3][tid][1];
        const float Z = s_wsum[0][tid][2] + s_wsum[1][tid][2] + s_wsum[2][tid][2] + s_wsum[3][tid][2];
        const float n = fmaxf(s_wsum[0][tid][3] + s_wsum[1][tid][3] + s_wsum[2][tid][3] + s_wsum[3][tid][3], 1.f);
        s_cent[tid * 3 + 0] = X / n;
        s_cent[tid * 3 + 1] = Y / n;
        s_cent[tid * 3 + 2] = Z / n;
    }
    __syncthreads();

    // ---------- Phase 2: distance loss on this block's 2048-pt slice ----------
    const int n0 = j * (NN / BLK_PER_B) + tid * 4;
    float sm = 0.f;
    #pragma unroll
    for (int it = 0; it < 2; ++it) {
        const int n = n0 + it * 1024;
        const float4 xv = *(const float4*)&sub[((size_t)b * 3 + 0) * NN + n];
        const float4 yv = *(const float4*)&sub[((size_t)b * 3 + 1) * NN + n];
        const float4 zv = *(const float4*)&sub[((size_t)b * 3 + 2) * NN + n];
        const float4 dv = *(const float4*)&disp[(size_t)b * NN + n];
        const float xs[4] = {xv.x, xv.y, xv.z, xv.w};
        const float ys[4] = {yv.x, yv.y, yv.z, yv.w};
        const float zs[4] = {zv.x, zv.y, zv.z, zv.w};
        const float ds[4] = {dv.x, dv.y, dv.z, dv.w};
        #pragma unroll
        for (int k = 0; k < 4; ++k) {
            float mn = 1e30f;
            #pragma unroll
            for (int c = 0; c < NC; ++c) {
                const float dx = xs[k] - s_cent[c * 3 + 0];
                const float dy = ys[k] - s_cent[c * 3 + 1];
                const float dz = zs[k] - s_cent[c * 3 + 2];
                mn = fminf(mn, dx * dx + dy * dy + dz * dz);
            }
            const float v  = ds[k] - sqrtf(mn);
            const float av = fabsf(v);
            sm += (av < 1.f) ? 0.5f * v * v : (av - 0.5f);
        }
    }

    #pragma unroll
    for (int o = 32; o > 0; o >>= 1) sm += __shfl_down(sm, o);

    __shared__ float s_part[4];
    if (lane == 0) s_part[wave] = sm;

    // chamfer + separation: only on the first block of each batch
    __shared__ float s_chamfer;
    if (j == 0) {
        __shared__ float s_D[NC][NC];
        if (tid < NC * NC) {
            const int cp = tid / NC, c = tid % NC;
            const float dx = cpred[(size_t)b * 3 * NC + 0 * NC + cp] - s_cent[c * 3 + 0];
            const float dy = cpred[(size_t)b * 3 * NC + 1 * NC + cp] - s_cent[c * 3 + 1];
            const float dz = cpred[(size_t)b * 3 * NC + 2 * NC + cp] - s_cent[c * 3 + 2];
            s_D[cp][c] = dx * dx + dy * dy + dz * dz;
        }
        __syncthreads();
        __shared__ float s_contrib[NC];
        if (tid < NC) {
            float mn = s_D[0][tid];                  // l1: min over cp
            #pragma unroll
            for (int cp = 1; cp < NC; ++cp) mn = fminf(mn, s_D[cp][tid]);
            float m1 = 1e30f, m2 = 1e30f;            // row cp=tid: two smallest
            #pragma unroll
            for (int c = 0; c < NC; ++c) {
                const float d = sqrtf(s_D[tid][c]);
                if (d < m1) { m2 = m1; m1 = d; }
                else if (d < m2) { m2 = d; }
            }
            s_contrib[tid] = mn + m1 * m1 + 0.1f * (m1 / m2);
        }
        __syncthreads();
        if (tid == 0) {
            float s = 0.f;
            #pragma unroll
            for (int c = 0; c < NC; ++c) s += s_contrib[c];
            s_chamfer = s;
        }
    } else if (tid == 0) {
        s_chamfer = 0.f;
    }
    __syncthreads();

    if (tid == 0)
        ws[WS_DIST + blockIdx.x] =
            s_part[0] + s_part[1] + s_part[2] + s_part[3] + s_chamfer;
}

// 1-block final reduction: 256 partial slots -> scalar. Stream order
// guarantees visibility of the fused kernel's global writes. No counters,
// no workspace-state assumptions.
__global__ __launch_bounds__(256) void reduce_kernel(const float* __restrict__ ws,
                                                     float* __restrict__ out) {
    const int tid = threadIdx.x;
    float acc = ws[WS_DIST + tid];   // exactly one slot per thread (NBLK_B==256)
    #pragma unroll
    for (int o = 32; o > 0; o >>= 1) acc += __shfl_down(acc, o);
    __shared__ float s_fin[4];
    if ((tid & 63) == 0) s_fin[tid >> 6] = acc;
    __syncthreads();
    if (tid == 0)
        *out = s_fin[0] + s_fin[1] + s_fin[2] + s_fin[3];
}

extern "C" void kernel_launch(void* const* d_in, const int* in_sizes, int n_in,
                              void* d_out, int out_size, void* d_ws, size_t ws_size,
                              hipStream_t stream) {
    const float* disp   = (const float*)d_in[0]; // [B,N]
    const float* sub    = (const float*)d_in[1]; // [B,3,N]
    const float* cpred  = (const float*)d_in[2]; // [B,3,C]
    const float* origin = (const float*)d_in[3]; // [B,9,P]
    const int*   target = (const int*)d_in[4];   // [B,P]

    float* out = (float*)d_out;
    float* ws  = (float*)d_ws;

    fused_loss_kernel<<<NBLK_B, 256, 0, stream>>>(disp, sub, cpred, origin, target, ws);
    reduce_kernel<<<1, 256, 0, stream>>>(ws, out);
}